// Round 3
// baseline (145.921 us; speedup 1.0000x reference)
//
#include <hip/hip_runtime.h>

// out = conv2d(poly(img), W, stride=1, pad=1) / 27, poly(v) = A0 + A1*v + A2*v^2
// (identity-kernel branch contributes exactly zero; 1/27 folded into poly).
// Implicit GEMM on bf16 MFMA: A = weights (M=o), B = poly(img) (N = spatial x),
// K = (ky,kx,c) = 576, mfma_f32_32x32x16_bf16.
//
// R7 = R5/R6 with the NaN root-cause fixed: stage_write used `ilds + buf*12672`
// (elements == 25344 B) while the MFMA reader used `ilds + buf*6336` (elements ==
// 12672 B, the true buffer size). buf==1 reads hit uninitialized LDS -> NaN.
// One-line fix: write stride = 6336 elements. Design unchanged:
//  - T14 async-STAGE split: global loads for chunk k+1 issued BEFORE the MFMA loop
//    of chunk k, poly+ds_write AFTER it -> load latency hides under compute.
//  - x-split blocks (1024 blocks, 64-wide x tiles): per-wave acc 64->32 regs, making
//    room for the 16-reg T14 load buffer under the 128-reg/16-wave occupancy tier.
//  - Single-pass epilogue through a 64 KB LDS transpose buffer: 2 barriers vs 8.

typedef __bf16 bf16;
typedef __attribute__((ext_vector_type(4))) __bf16 bf16x4;
typedef __attribute__((ext_vector_type(8))) __bf16 bf16x8;
typedef __attribute__((ext_vector_type(16))) float f32x16;

static constexpr float A0 = -0.000287f / 27.0f;
static constexpr float A1 =  0.266f    / 27.0f;
static constexpr float A2 = -0.1097f   / 27.0f;

#define NN 16
#define CI 64
#define HH 128
#define WW 128
#define OO 64

// Repack weights [O][C][3][3] fp32 -> [slice=ky*3+kx][cc8=c/8][o][cj=c%8] bf16.
__global__ void repack_w(const float* __restrict__ w, bf16* __restrict__ wrb) {
    int idx = blockIdx.x * 256 + threadIdx.x;        // 9*8*64*8 = 36864
    if (idx >= 9 * 8 * 64 * 8) return;
    int cj    = idx & 7;
    int o     = (idx >> 3) & 63;
    int cc8   = (idx >> 9) & 7;
    int slice = idx >> 12;
    int ky = slice / 3, kx = slice - ky * 3;
    int c = cc8 * 8 + cj;
    wrb[idx] = (bf16)w[((o * CI + c) * 3 + ky) * 3 + kx];
}

__global__ __launch_bounds__(512, 4) void conv_mfma(const float* __restrict__ img,
                                                    const bf16* __restrict__ wrb,
                                                    float* __restrict__ out) {
    // Staging: [buf 2][r 6][ccl 2][xp 66][cj 8] bf16 = 2 x 6336 elem = 2 x 12672 B.
    // Epilogue overlay: [o 64][y 4][x 64] f32 = 65536 B (single pass).
    __shared__ __align__(16) char smem[65536];
    bf16*  ilds = (bf16*)smem;
    float* elds = (float*)smem;

    const int tid = threadIdx.x;
    const int b   = blockIdx.x;          // 1024 = n(16) x ytile(32) x xhalf(2)
    const int X0  = (b & 1) * 64;
    const int y0  = ((b >> 1) & 31) * 4;
    const int n   = b >> 6;

    const int wv   = tid >> 6;
    const int lane = tid & 63;
    const int lm   = lane & 31;      // A: o-row / B: x-col / C: col
    const int half = lane >> 5;      // k-half selector (which cc8 of the pair)
    const int yl   = wv >> 1;        // output row within tile
    const int xw   = (wv & 1) * 32;  // x sub-tile within the 64-wide block tile

    // ---- T14 staging, split into issue-early loads and write-late finish. ----
    // Sub-items: t in [0,408): c4 = t>=204 (channel nibble), id = t - 204*c4,
    // id -> (r = id/34, ccl = (id%34)/17, xs = id%17). xs<16: float4 at
    // x = X0+4*xs (covers xp = 4*xs+1 .. 4*xs+4); xs==16: the two halo columns.
    auto stage_load = [&](int chunk, float4* v) {
        if (tid >= 408) return;
        const int c4  = (tid >= 204) ? 1 : 0;
        const int id  = tid - 204 * c4;
        const int r   = id / 34;
        const int rem = id - r * 34;
        const int ccl = rem / 17;
        const int xs  = rem - ccl * 17;
        const int yi  = y0 - 1 + r;
        const bool yok = (unsigned)yi < 128u;
        const int cb  = chunk * 16 + ccl * 8 + c4 * 4;
        const float* p = img + ((n * CI + cb) * HH + yi) * WW;
        if (xs < 16) {
            if (yok) {
                #pragma unroll
                for (int j = 0; j < 4; ++j)
                    v[j] = *(const float4*)(p + j * HH * WW + X0 + 4 * xs);   // 16B aligned
            }
        } else {
            // halo columns: left x=X0-1 (valid iff X0==64), right x=X0+64 (valid iff X0==0)
            #pragma unroll
            for (int j = 0; j < 4; ++j) { v[j].x = 0.0f; v[j].y = 0.0f; }
            if (yok && X0 == 64) {
                #pragma unroll
                for (int j = 0; j < 4; ++j) v[j].x = p[j * HH * WW + 63];
            }
            if (yok && X0 == 0) {
                #pragma unroll
                for (int j = 0; j < 4; ++j) v[j].y = p[j * HH * WW + 64];
            }
        }
    };

    auto stage_write = [&](int buf, float4* v) {
        if (tid >= 408) return;
        const int c4  = (tid >= 204) ? 1 : 0;
        const int id  = tid - 204 * c4;
        const int r   = id / 34;
        const int rem = id - r * 34;
        const int ccl = rem / 17;
        const int xs  = rem - ccl * 17;
        const int yi  = y0 - 1 + r;
        const bool yok = (unsigned)yi < 128u;
        bf16* rowp = ilds + buf * 6336 + ((r * 2 + ccl) * 66) * 8 + c4 * 4;
        if (xs < 16) {
            #pragma unroll
            for (int c = 0; c < 4; ++c) {
                bf16x4 pk;
                #pragma unroll
                for (int j = 0; j < 4; ++j) {
                    const float x = (c == 0) ? v[j].x : (c == 1) ? v[j].y
                                   : (c == 2) ? v[j].z : v[j].w;
                    pk[j] = yok ? (bf16)(A0 + x * (A1 + A2 * x)) : (bf16)0.0f;
                }
                *(bf16x4*)(rowp + (4 * xs + 1 + c) * 8) = pk;
            }
        } else {
            bf16x4 pl, pr;
            const bool lok = yok && (X0 == 64);
            const bool rok = yok && (X0 == 0);
            #pragma unroll
            for (int j = 0; j < 4; ++j) {
                const float xl = v[j].x, xr = v[j].y;
                pl[j] = lok ? (bf16)(A0 + xl * (A1 + A2 * xl)) : (bf16)0.0f;
                pr[j] = rok ? (bf16)(A0 + xr * (A1 + A2 * xr)) : (bf16)0.0f;
            }
            *(bf16x4*)(rowp + 0 * 8)  = pl;   // xp=0   (xi=X0-1 or conv pad)
            *(bf16x4*)(rowp + 65 * 8) = pr;   // xp=65  (xi=X0+64 or conv pad)
        }
    };

    f32x16 acc[2];
    #pragma unroll
    for (int k = 0; k < 16; ++k) { acc[0][k] = 0.0f; acc[1][k] = 0.0f; }

    const bf16x8* wfr = (const bf16x8*)wrb;

    float4 v[4];
    stage_load(0, v);
    stage_write(0, v);

    for (int chunk = 0; chunk < 4; ++chunk) {
        __syncthreads();                           // buf[chunk&1] staged & visible
        if (chunk < 3) stage_load(chunk + 1, v);   // issue loads, NO wait here
        const bf16x8* ifr = (const bf16x8*)(ilds + (chunk & 1) * 6336);
        const int cc8g = chunk * 2 + half;
        #pragma unroll
        for (int ky = 0; ky < 3; ++ky) {
            const int rr2 = (yl + ky) * 2 + half;
            #pragma unroll
            for (int kx = 0; kx < 3; ++kx) {
                const int slice = ky * 3 + kx;
                bf16x8 a0 = wfr[(slice * 8 + cc8g) * 64 + lm];        // weights, L1-hot
                bf16x8 a1 = wfr[(slice * 8 + cc8g) * 64 + 32 + lm];
                bf16x8 b0 = ifr[rr2 * 66 + xw + lm + kx];             // conflict-free b128
                acc[0] = __builtin_amdgcn_mfma_f32_32x32x16_bf16(a0, b0, acc[0], 0, 0, 0);
                acc[1] = __builtin_amdgcn_mfma_f32_32x32x16_bf16(a1, b0, acc[1], 0, 0, 0);
            }
        }
        if (chunk < 3) stage_write((chunk + 1) & 1, v);  // poly+LDS write after compute
    }

    // ---- Epilogue: single pass, all 64 o-rows through LDS, dwordx4 stores. ----
    // C/D layout: col = lane&31 (x), row-in-32 = (rg&3) + 8*(rg>>2) + 4*half (o).
    __syncthreads();                   // staging LDS reads done; overlay is safe
    #pragma unroll
    for (int i = 0; i < 2; ++i) {
        #pragma unroll
        for (int rg = 0; rg < 16; ++rg) {
            const int o64 = (rg & 3) + 8 * (rg >> 2) + 4 * half + 32 * i;
            elds[(o64 * 4 + yl) * 64 + xw + lm] = acc[i][rg];
        }
    }
    __syncthreads();
    // 4096 float4s: idx -> (o = idx>>6, yy = (idx>>4)&3, x4 = idx&15).
    #pragma unroll
    for (int j = 0; j < 8; ++j) {
        const int idx = tid + j * 512;
        const int x4  = idx & 15;
        const int yy  = (idx >> 4) & 3;
        const int o   = idx >> 6;
        float4 vv = ((const float4*)elds)[idx];                       // lane-contiguous
        float* dstp = out + ((n * OO + o) * HH + (y0 + yy)) * WW + X0 + x4 * 4;
        *(float4*)dstp = vv;                                          // 256 B/row segment
    }
}

extern "C" void kernel_launch(void* const* d_in, const int* in_sizes, int n_in,
                              void* d_out, int out_size, void* d_ws, size_t ws_size,
                              hipStream_t stream) {
    const float* img = (const float*)d_in[0];
    const float* w   = (const float*)d_in[1];
    // d_in[2] (identity_kernel) unused: its branch convolves exact zeros.
    float* out = (float*)d_out;
    bf16* wrb  = (bf16*)d_ws;    // 36864 bf16 = 73728 B repacked weights

    repack_w<<<(9 * 8 * 64 * 8 + 255) / 256, 256, 0, stream>>>(w, wrb);
    conv_mfma<<<NN * (HH / 4) * 2, 512, 0, stream>>>(img, wrb, out);
}

// Round 4
// 139.791 us; speedup vs baseline: 1.0438x; 1.0438x over previous
//
#include <hip/hip_runtime.h>

// out = conv2d(poly(img), W, stride=1, pad=1) / 27, poly(v) = A0 + A1*v + A2*v^2
// (identity-kernel branch contributes exactly zero; 1/27 folded into poly).
// Implicit GEMM on bf16 MFMA: A = weights (M=o), B = poly(img) (N = spatial x),
// K = (ky,kx,c) = 576, mfma_f32_32x32x16_bf16.
//
// R8 = R4 geometry restored (128-wide rows, 512 blocks — R7's x-split cost +49%
// FETCH from cross-XCD halo lines and 5.5x bank conflicts) + two changes:
//  1. Dead-register software prefetch: one global_load_dword per 128-B line of
//     chunk k+2 issued right after the chunk barrier, result sunk into
//     asm volatile (no consumer -> never stalls; keeps HBM busy across phase
//     boundaries; real stage loads become L2 hits). Zero buffer registers,
//     unlike T14 which would push past the 128-reg/2-block occupancy cliff.
//  2. 2-pass epilogue (32 o-rows per pass through a 64 KB LDS overlay):
//     epilogue barriers 8 -> 4. LDS 65536 B keeps 2 blocks/CU (grid-limited).

typedef __bf16 bf16;
typedef __attribute__((ext_vector_type(8))) __bf16 bf16x8;
typedef __attribute__((ext_vector_type(16))) float f32x16;

static constexpr float A0 = -0.000287f / 27.0f;
static constexpr float A1 =  0.266f    / 27.0f;
static constexpr float A2 = -0.1097f   / 27.0f;

#define NN 16
#define CI 64
#define HH 128
#define WW 128
#define OO 64

// Repack weights [O][C][3][3] fp32 -> [slice=ky*3+kx][cc8=c/8][o][cj=c%8] bf16.
__global__ void repack_w(const float* __restrict__ w, bf16* __restrict__ wrb) {
    int idx = blockIdx.x * 256 + threadIdx.x;        // 9*8*64*8 = 36864
    if (idx >= 9 * 8 * 64 * 8) return;
    int cj    = idx & 7;
    int o     = (idx >> 3) & 63;
    int cc8   = (idx >> 9) & 7;
    int slice = idx >> 12;
    int ky = slice / 3, kx = slice - ky * 3;
    int c = cc8 * 8 + cj;
    wrb[idx] = (bf16)w[((o * CI + c) * 3 + ky) * 3 + kx];
}

__global__ __launch_bounds__(512, 4) void conv_mfma(const float* __restrict__ img,
                                                    const bf16* __restrict__ wrb,
                                                    float* __restrict__ out) {
    // Staging: [buf 2][r 6][ccl 2][xp 130][cj 8] bf16 = 2 x 12480 elem = 49920 B.
    // Epilogue overlay: [o32 32][y 4][x 128] f32 = 65536 B (2 passes).
    __shared__ __align__(16) char smem[65536];
    bf16*  ilds = (bf16*)smem;
    float* elds = (float*)smem;

    const int tid = threadIdx.x;
    const int b   = blockIdx.x;
    const int y0  = (b & 31) * 4;
    const int n   = b >> 5;

    const int wv   = tid >> 6;
    const int lane = tid & 63;
    const int lm   = lane & 31;      // A: o-row / B: x-col / C: col
    const int half = lane >> 5;      // k-half selector (which cc8 of the pair)
    const int yl   = wv >> 1;
    const int Xh   = (wv & 1) * 64;

    // Prefetch-touch: one dword per 128-B line of chunk's staging footprint.
    // 384 = 6 rows x 16 ch x 4 lines. Dead result kept live via empty asm.
    auto touch = [&](int chunk) {
        if (tid < 384) {
            const int r  = tid >> 6;         // 0..5
            const int ch = (tid >> 2) & 15;  // 0..15
            const int xl = tid & 3;          // 0..3 (128-B line index)
            const int yi = y0 - 1 + r;
            if ((unsigned)yi < 128u) {
                float t = img[((n * CI + chunk * 16 + ch) * HH + yi) * WW + xl * 32];
                asm volatile("" :: "v"(t));  // keep load, no consumer (rule #17)
            }
        }
    };

    // Stage poly(img) chunk (16 channels) into LDS buffer buf (R4-verbatim).
    auto stage = [&](int chunk, int buf) {
        const int cbase = chunk * 16;
        bf16* dst = ilds + buf * 12480;
        for (int t = tid; t < 780; t += 512) {     // 6r * 2ccl * 65
            int r   = t / 130;
            int rem = t - r * 130;
            int ccl = rem / 65;
            int xh  = rem - ccl * 65;
            int yi  = y0 - 1 + r;
            bf16* rowp = dst + (r * 2 + ccl) * (130 * 8);
            if (xh < 64) {
                bf16x8 pk0, pk1;
                if ((unsigned)yi < 128u) {
                    const float* p = img + ((n * CI + cbase + ccl * 8) * HH + yi) * WW + 2 * xh;
                    #pragma unroll
                    for (int j = 0; j < 8; ++j) {
                        float2 v = *(const float2*)(p + j * HH * WW);   // 8B aligned
                        pk0[j] = (bf16)(A0 + v.x * (A1 + A2 * v.x));
                        pk1[j] = (bf16)(A0 + v.y * (A1 + A2 * v.y));
                    }
                } else {
                    #pragma unroll
                    for (int j = 0; j < 8; ++j) { pk0[j] = (bf16)0.0f; pk1[j] = (bf16)0.0f; }
                }
                *(bf16x8*)(rowp + (2 * xh + 1) * 8) = pk0;
                *(bf16x8*)(rowp + (2 * xh + 2) * 8) = pk1;
            } else {
                bf16x8 z;
                #pragma unroll
                for (int j = 0; j < 8; ++j) z[j] = (bf16)0.0f;
                *(bf16x8*)(rowp + 0) = z;            // xp=0   (xi=-1, conv pad)
                *(bf16x8*)(rowp + 129 * 8) = z;      // xp=129 (xi=128, conv pad)
            }
        }
    };

    f32x16 acc[2][2];
    #pragma unroll
    for (int i = 0; i < 2; ++i)
        #pragma unroll
        for (int j = 0; j < 2; ++j)
            #pragma unroll
            for (int k = 0; k < 16; ++k) acc[i][j][k] = 0.0f;

    const bf16x8* wfr = (const bf16x8*)wrb;

    touch(1);        // lines for chunk 1 start streaming behind stage(0)'s demand
    stage(0, 0);

    for (int chunk = 0; chunk < 4; ++chunk) {
        __syncthreads();
        if (chunk < 2) touch(chunk + 2);           // prefetch 2 chunks ahead
        if (chunk < 3) stage(chunk + 1, (chunk + 1) & 1);   // L2-hot loads
        const bf16x8* ifr = (const bf16x8*)(ilds + (chunk & 1) * 12480);
        const int cc8g = chunk * 2 + half;
        #pragma unroll
        for (int ky = 0; ky < 3; ++ky) {
            const int r = yl + ky;
            #pragma unroll
            for (int kx = 0; kx < 3; ++kx) {
                const int slice = ky * 3 + kx;
                bf16x8 a0 = wfr[(slice * 8 + cc8g) * 64 + lm];        // weights, L1-hot
                bf16x8 a1 = wfr[(slice * 8 + cc8g) * 64 + 32 + lm];
                const int ib = (r * 2 + half) * 130 + Xh + lm + kx;   // conflict-free b128
                bf16x8 b0 = ifr[ib];
                bf16x8 b1 = ifr[ib + 32];
                acc[0][0] = __builtin_amdgcn_mfma_f32_32x32x16_bf16(a0, b0, acc[0][0], 0, 0, 0);
                acc[0][1] = __builtin_amdgcn_mfma_f32_32x32x16_bf16(a0, b1, acc[0][1], 0, 0, 0);
                acc[1][0] = __builtin_amdgcn_mfma_f32_32x32x16_bf16(a1, b0, acc[1][0], 0, 0, 0);
                acc[1][1] = __builtin_amdgcn_mfma_f32_32x32x16_bf16(a1, b1, acc[1][1], 0, 0, 0);
            }
        }
    }

    // ---- Epilogue: 2 passes of 32 o-rows through LDS, stores as dwordx4. ----
    // C/D layout: col = lane&31 (x), row-in-32 = (rg&3) + 8*(rg>>2) + 4*half (o).
    // acc[p][*] holds o in [32p, 32p+32): a0 covers o=lm, a1 covers o=32+lm.
    #pragma unroll
    for (int p = 0; p < 2; ++p) {
        __syncthreads();                   // LDS free (staging/previous pass read done)
        #pragma unroll
        for (int xt = 0; xt < 2; ++xt) {
            const int x = Xh + xt * 32 + lm;
            #pragma unroll
            for (int rg = 0; rg < 16; ++rg) {
                const int o32 = (rg & 3) + 8 * (rg >> 2) + 4 * half;
                elds[(o32 * 4 + yl) * 128 + x] = acc[p][xt][rg];
            }
        }
        __syncthreads();
        // 4096 float4s: idx -> (o32 = idx>>7, yy = (idx>>5)&3, x4 = idx&31).
        #pragma unroll
        for (int j = 0; j < 8; ++j) {
            const int idx = tid + j * 512;
            const int x4  = idx & 31;
            const int yy  = (idx >> 5) & 3;
            const int o32 = idx >> 7;
            float4 v = ((const float4*)elds)[idx];                    // lane-contiguous
            float* dstp = out + ((n * OO + p * 32 + o32) * HH + (y0 + yy)) * WW + x4 * 4;
            *(float4*)dstp = v;                                       // 1 KB/wave-instr
        }
    }
}

extern "C" void kernel_launch(void* const* d_in, const int* in_sizes, int n_in,
                              void* d_out, int out_size, void* d_ws, size_t ws_size,
                              hipStream_t stream) {
    const float* img = (const float*)d_in[0];
    const float* w   = (const float*)d_in[1];
    // d_in[2] (identity_kernel) unused: its branch convolves exact zeros.
    float* out = (float*)d_out;
    bf16* wrb  = (bf16*)d_ws;    // 36864 bf16 = 73728 B repacked weights

    repack_w<<<(9 * 8 * 64 * 8 + 255) / 256, 256, 0, stream>>>(w, wrb);
    conv_mfma<<<NN * (HH / 4), 512, 0, stream>>>(img, wrb, out);
}

// Round 5
// 128.291 us; speedup vs baseline: 1.1374x; 1.0896x over previous
//
#include <hip/hip_runtime.h>

// out = conv2d(poly(img), W, stride=1, pad=1) / 27, poly(v) = A0 + A1*v + A2*v^2
// (identity-kernel branch contributes exactly zero; 1/27 folded into poly).
// Implicit GEMM on bf16 MFMA: A = weights (M=o), B = poly(img) (N = spatial x),
// K = (ky,kx,c) = 576, mfma_f32_32x32x16_bf16.
//
// R9: async global->LDS DMA staging (R8's touch-prefetch thrashed L2: FETCH 49->85 MB).
//  - Per chunk: global_load_lds (dwordx4) DMAs the raw f32 16-ch slab into LDS in
//    6 instrs/wave (deep MLP, zero VGPR), then an LDS-local transform applies poly
//    and packs bf16 into the R4 staging layout. No per-thread load->vmcnt->poly
//    serialization; dma(k+1) streams during MFMA(k) + barrier drain.
//  - Chunk-order stagger ((b>>8)&1 -> start at chunk 2): co-resident block pairs
//    anti-phase their DMA bursts. K-order is commutative (absmax headroom 3.7x).
//  - Direct global stores from acc (each half-wave = one full 128-B line): drops
//    the 64 KB epilogue overlay + 4 barriers. LDS = 49152 raw + 24960 bf16 =
//    74112 B dynamic (hipFuncSetAttribute), 2 blocks/CU (148 KB <= 160 KB).

typedef __bf16 bf16;
typedef __attribute__((ext_vector_type(8))) __bf16 bf16x8;
typedef __attribute__((ext_vector_type(16))) float f32x16;

static constexpr float A0 = -0.000287f / 27.0f;
static constexpr float A1 =  0.266f    / 27.0f;
static constexpr float A2 = -0.1097f   / 27.0f;

#define NN 16
#define CI 64
#define HH 128
#define WW 128
#define OO 64
#define LDS_BYTES 74112   // 49152 B raw f32 + 24960 B bf16 staging

// Repack weights [O][C][3][3] fp32 -> [slice=ky*3+kx][cc8=c/8][o][cj=c%8] bf16.
__global__ void repack_w(const float* __restrict__ w, bf16* __restrict__ wrb) {
    int idx = blockIdx.x * 256 + threadIdx.x;        // 9*8*64*8 = 36864
    if (idx >= 9 * 8 * 64 * 8) return;
    int cj    = idx & 7;
    int o     = (idx >> 3) & 63;
    int cc8   = (idx >> 9) & 7;
    int slice = idx >> 12;
    int ky = slice / 3, kx = slice - ky * 3;
    int c = cc8 * 8 + cj;
    wrb[idx] = (bf16)w[((o * CI + c) * 3 + ky) * 3 + kx];
}

__global__ __launch_bounds__(512, 4) void conv_mfma(const float* __restrict__ img,
                                                    const bf16* __restrict__ wrb,
                                                    float* __restrict__ out) {
    // raw:  [r 6][ch 16][x 128] f32   = 49152 B  (DMA target, linear lane order)
    // ilds: [r2 12][xp 130][cj 8] bf16 = 24960 B (MFMA B staging, R4 layout)
    extern __shared__ __align__(16) char smem[];
    float* raw  = (float*)smem;
    bf16*  ilds = (bf16*)(smem + 49152);

    const int tid = threadIdx.x;
    const int b   = blockIdx.x;
    const int y0  = (b & 31) * 4;
    const int n   = b >> 5;

    const int wv   = tid >> 6;
    const int lane = tid & 63;
    const int lm   = lane & 31;      // A: o-row / B: x-col / C: col
    const int half = lane >> 5;      // k-half selector (which cc8 of the pair)
    const int yl   = wv >> 1;
    const int Xh   = (wv & 1) * 64;

    // DMA one 16-ch chunk into raw. Instr i of wave wv covers row r=i,
    // ch = {2wv, 2wv+1} split by lane-half; 64 lanes x 16 B = two 512-B rows.
    // yi is wave-uniform per instr (guard is uniform). Invalid rows skipped
    // (stale raw is zeroed by the transform's yok test).
    auto dma = [&](int chunk) {
        const int ch = 2 * wv + half;
        const int x0 = (lane & 31) * 4;
        #pragma unroll
        for (int i = 0; i < 6; ++i) {
            const int yi = y0 - 1 + i;
            if ((unsigned)yi < 128u) {
                const float* g = img + ((n * CI + chunk * 16 + ch) * HH + yi) * WW + x0;
                __builtin_amdgcn_global_load_lds(
                    (const __attribute__((address_space(1))) void*)g,
                    (__attribute__((address_space(3))) void*)(raw + (wv + 8 * i) * 256),
                    16, 0, 0);
            }
        }
    };

    // Transform: poly(raw f32) -> bf16 staging (LDS-local; R4 stage body shape).
    // 780 items = 6r * 2ccl * 65xh; xh<64 handles xp = 2xh+1, 2xh+2; xh==64 halo.
    auto transform = [&]() {
        for (int t = tid; t < 780; t += 512) {
            int r   = t / 130;
            int rem = t - r * 130;
            int ccl = rem / 65;
            int xh  = rem - ccl * 65;
            int yi  = y0 - 1 + r;
            bf16* rowp = ilds + (r * 2 + ccl) * (130 * 8);
            if (xh < 64) {
                bf16x8 pk0, pk1;
                if ((unsigned)yi < 128u) {
                    const float* p = raw + (r * 16 + ccl * 8) * 128 + 2 * xh;
                    #pragma unroll
                    for (int j = 0; j < 8; ++j) {
                        float2 v = *(const float2*)(p + j * 128);   // LDS b64, conflict-free-ish
                        pk0[j] = (bf16)(A0 + v.x * (A1 + A2 * v.x));
                        pk1[j] = (bf16)(A0 + v.y * (A1 + A2 * v.y));
                    }
                } else {
                    #pragma unroll
                    for (int j = 0; j < 8; ++j) { pk0[j] = (bf16)0.0f; pk1[j] = (bf16)0.0f; }
                }
                *(bf16x8*)(rowp + (2 * xh + 1) * 8) = pk0;
                *(bf16x8*)(rowp + (2 * xh + 2) * 8) = pk1;
            } else {
                bf16x8 z;
                #pragma unroll
                for (int j = 0; j < 8; ++j) z[j] = (bf16)0.0f;
                *(bf16x8*)(rowp + 0) = z;            // xp=0   (xi=-1, conv pad)
                *(bf16x8*)(rowp + 129 * 8) = z;      // xp=129 (xi=128, conv pad)
            }
        }
    };

    f32x16 acc[2][2];
    #pragma unroll
    for (int i = 0; i < 2; ++i)
        #pragma unroll
        for (int j = 0; j < 2; ++j)
            #pragma unroll
            for (int k = 0; k < 16; ++k) acc[i][j][k] = 0.0f;

    const bf16x8* wfr = (const bf16x8*)wrb;
    const bf16x8* ifr = (const bf16x8*)ilds;

    // Chunk-order stagger: co-resident pair (b, b+256) starts 2 chunks apart.
    const int corder = ((b >> 8) & 1) * 2;

    dma(corder);
    __syncthreads();                               // implicit vmcnt(0): raw ready

    for (int j = 0; j < 4; ++j) {
        const int cc = (corder + j) & 3;
        transform();
        __syncthreads();                           // bf16 ready; raw free
        if (j < 3) dma((corder + j + 1) & 3);      // streams during MFMA + drain
        const int cc8g = cc * 2 + half;
        #pragma unroll
        for (int ky = 0; ky < 3; ++ky) {
            const int r = yl + ky;
            #pragma unroll
            for (int kx = 0; kx < 3; ++kx) {
                const int slice = ky * 3 + kx;
                bf16x8 a0 = wfr[(slice * 8 + cc8g) * 64 + lm];        // weights, L1-hot
                bf16x8 a1 = wfr[(slice * 8 + cc8g) * 64 + 32 + lm];
                const int ib = (r * 2 + half) * 130 + Xh + lm + kx;   // conflict-free b128
                bf16x8 b0 = ifr[ib];
                bf16x8 b1 = ifr[ib + 32];
                acc[0][0] = __builtin_amdgcn_mfma_f32_32x32x16_bf16(a0, b0, acc[0][0], 0, 0, 0);
                acc[0][1] = __builtin_amdgcn_mfma_f32_32x32x16_bf16(a0, b1, acc[0][1], 0, 0, 0);
                acc[1][0] = __builtin_amdgcn_mfma_f32_32x32x16_bf16(a1, b0, acc[1][0], 0, 0, 0);
                acc[1][1] = __builtin_amdgcn_mfma_f32_32x32x16_bf16(a1, b1, acc[1][1], 0, 0, 0);
            }
        }
        if (j < 3) __syncthreads();                // drains dma; bf16 free for next
    }

    // ---- Epilogue: direct stores. Half-wave = 32 lanes x 4 B = one full
    // 128-B line per (o,y) segment; every output line written exactly once. ----
    // C/D layout: col = lane&31 (x), row-in-32 = (rg&3) + 8*(rg>>2) + 4*half (o).
    const int ybase = (n * OO * HH + (y0 + yl)) * WW;
    #pragma unroll
    for (int p = 0; p < 2; ++p)
        #pragma unroll
        for (int xt = 0; xt < 2; ++xt) {
            const int x = Xh + xt * 32 + lm;
            #pragma unroll
            for (int rg = 0; rg < 16; ++rg) {
                const int o = (rg & 3) + 8 * (rg >> 2) + 4 * half + 32 * p;
                out[ybase + o * (HH * WW) + x] = acc[p][xt][rg];
            }
        }
}

extern "C" void kernel_launch(void* const* d_in, const int* in_sizes, int n_in,
                              void* d_out, int out_size, void* d_ws, size_t ws_size,
                              hipStream_t stream) {
    const float* img = (const float*)d_in[0];
    const float* w   = (const float*)d_in[1];
    // d_in[2] (identity_kernel) unused: its branch convolves exact zeros.
    float* out = (float*)d_out;
    bf16* wrb  = (bf16*)d_ws;    // 36864 bf16 = 73728 B repacked weights

    static bool attr_done = false;
    if (!attr_done) {
        (void)hipFuncSetAttribute((const void*)conv_mfma,
                                  hipFuncAttributeMaxDynamicSharedMemorySize, LDS_BYTES);
        attr_done = true;
    }

    repack_w<<<(9 * 8 * 64 * 8 + 255) / 256, 256, 0, stream>>>(w, wrb);
    conv_mfma<<<NN * (HH / 4), 512, LDS_BYTES, stream>>>(img, wrb, out);
}